// Round 1
// baseline (903.381 us; speedup 1.0000x reference)
//
#include <hip/hip_runtime.h>
#include <hip/hip_bf16.h>
#include <stdint.h>

// Problem constants (from reference): B=8,S=2048,IN=4096,OUT=4096,G=32
#define M_TOT 16384   // B*S
#define N_TOT 4096    // OUT
#define K_TOT 4096    // IN
#define NB    524288  // OUT*IN/G

// GEMM geometry: 256x256 tile, BK=64, 8 waves (2M x 4N), 8-phase schedule
// (m201 template: T2 swizzle + T3/T4 counted vmcnt + T5 setprio + T1 XCD).
#define BM 256
#define BN 256
#define BK 64
#define NT (K_TOT / BK)   // 64 K-tiles

typedef __attribute__((ext_vector_type(8))) __bf16 bf16x8;
typedef __attribute__((ext_vector_type(4))) float f32x4;

// Barrier with compiler-level memory fence (prevents LDS access motion across
// the raw s_barrier; we do NOT use __syncthreads — it drains vmcnt to 0, which
// is exactly the m97 stall we are removing).
#define BARF() do { asm volatile("" ::: "memory"); \
                    __builtin_amdgcn_s_barrier(); \
                    asm volatile("" ::: "memory"); } while (0)
#define VMW(n) asm volatile("s_waitcnt vmcnt(" #n ")" ::: "memory")

#define MFMA1(d, a, b) d = __builtin_amdgcn_mfma_f32_16x16x32_bf16(a, b, d, 0, 0, 0)
// One C-quadrant (2 m-frags x 4 n-frags) x K=64 (2 k-slices) = 16 MFMA.
#define MFMA_PAIR(mb, A0, A1) do { \
  _Pragma("unroll") \
  for (int j_ = 0; j_ < 4; ++j_) { \
    MFMA1(acc[mb][j_],     A0[0], bF[j_][0]); \
    MFMA1(acc[mb][j_],     A0[1], bF[j_][1]); \
    MFMA1(acc[(mb)+1][j_], A1[0], bF[j_][0]); \
    MFMA1(acc[(mb)+1][j_], A1[1], bF[j_][1]); \
  } \
} while (0)

// ---------------------------------------------------------------------------
// Kernel 1: dequantize int4-packed W -> bf16 [OUT, IN] row-major. (unchanged)
// ---------------------------------------------------------------------------
__global__ __launch_bounds__(256) void dequant_w(
    const int* __restrict__ packed,          // [NB, 16] int32, one byte each
    const float* __restrict__ scale,         // [NB] f32 (promoted from fp16)
    const int* __restrict__ mask,            // [NB] int32 (promoted from bool)
    __hip_bfloat16* __restrict__ wout)       // [OUT*IN] bf16
{
    int t = blockIdx.x * blockDim.x + threadIdx.x;   // 0 .. NB*4-1
    const int4 pk = ((const int4*)packed)[t];
    int nb = t >> 2;
    float se = scale[nb] * (mask[nb] ? 1.0f : 0.5f);
    int vals[4] = { pk.x, pk.y, pk.z, pk.w };
    __hip_bfloat16 o[8];
#pragma unroll
    for (int j = 0; j < 4; ++j) {
        int v = vals[j];
        o[2*j]   = __float2bfloat16((float)((v & 0xF) - 8) * se);
        o[2*j+1] = __float2bfloat16((float)(((v >> 4) & 0xF) - 8) * se);
    }
    int4 st;
    __builtin_memcpy(&st, o, 16);
    ((int4*)wout)[t] = st;
}

// ---------------------------------------------------------------------------
// Kernel 2: x fp32 -> bf16. (unchanged)
// ---------------------------------------------------------------------------
__global__ __launch_bounds__(256) void cvt_x(
    const float* __restrict__ x, __hip_bfloat16* __restrict__ xb)
{
    int t = blockIdx.x * blockDim.x + threadIdx.x;   // each handles 8 elems
    const float4* xp = (const float4*)x;
    float4 a = xp[2*t], b = xp[2*t + 1];
    __hip_bfloat16 o[8] = {
        __float2bfloat16(a.x), __float2bfloat16(a.y),
        __float2bfloat16(a.z), __float2bfloat16(a.w),
        __float2bfloat16(b.x), __float2bfloat16(b.y),
        __float2bfloat16(b.z), __float2bfloat16(b.w)
    };
    int4 st;
    __builtin_memcpy(&st, o, 16);
    ((int4*)xb)[t] = st;
}

// ---------------------------------------------------------------------------
// Kernel 3: C[M,N] = A[M,K] * W[N,K]^T + bias.  256x256 8-phase template.
//
// LDS: 2 buffers x (A 32KB + B 32KB) = 128 KB. Tile t -> buf[t&1].
// Each tile = 4 half-tiles {BH0,BH1,AH0,AH1}, half-tile = 128 rows x 64 k
//           = 2 global_load_lds issues (512 thr x 16B = 8KB covers 64 rows).
//
// T2 swizzle: logical (row, byte-col cb) stored at cb ^ ((row&7)<<4).
//   - ds_read side: lane reads row (..+lane&15), so XOR = (lane&7)<<4.
//   - stage side: global_load_lds dest is LINEAR (wave base + lane*16);
//     thread tid covers phys (row=tid>>3, pb=(tid&7)*16), so its GLOBAL
//     source col is pre-swizzled: pb ^ (((tid>>3)&7)<<4). Same involution
//     both sides (rule 21: both-sides-or-neither).
//
// 8-phase schedule (iteration = tiles ta=2it (buf0), tb=ta+1 (buf1)):
//   per tile, phase q computes m-frags {2q,2q+1} x all 4 n-frags x K=64.
//   ds_reads: q0: all B (8) + A-q0 (4) = 12;  q1: 4;  q2: A-q2 + A-q3 = 8;
//   q3: none (uses regs read in q2). => B region of a buffer is dead after
//   its q0 phase; A region dead after its q2 phase.
//   Stage slots (each = 1 half-tile whose dest region died last phase):
//     ph1: (tb,  AH1)   [buf1 A dead since prev-iter ph7]
//     ph2: (ta+2,BH0)   [buf0 B dead after ph1]
//     ph3: (ta+2,BH1)
//     ph4: (ta+2,AH0)   [buf0 A dead after ph3]  + vmcnt(6)
//     ph5: (ta+2,AH1)
//     ph6: (tb+2,BH0)   [buf1 B dead after ph5]
//     ph7: (tb+2,BH1)
//     ph8: (tb+2,AH0)   [buf1 A dead after ph7]  + vmcnt(6)
//   vmcnt(6) at ph4: outstanding = {tb-AH1(ph1), ta+2 x3 (ph2-4)} = 8; all
//   but newest 6 complete => tile tb fully resident before ph5's reads, and
//   exactly 3 half-tiles (ta+2) stay in flight. Symmetric at ph8. Loads are
//   issued in identical program order by every wave, so per-wave vmcnt
//   implies group-wide completeness after the barrier.
//   Last iteration: staged tile indices ">= NT" are clamped t-=2 (same
//   parity => same buffer, same bytes, dead regions) — harmless.
// ---------------------------------------------------------------------------
__global__ __launch_bounds__(512, 2) void gemm_bt(
    const __hip_bfloat16* __restrict__ A,   // [M_TOT, K_TOT] bf16
    const __hip_bfloat16* __restrict__ Bw,  // [N_TOT, K_TOT] bf16
    const float* __restrict__ bias,         // [N_TOT]
    float* __restrict__ C)                  // [M_TOT, N_TOT]
{
    __shared__ __align__(16) char lds[131072];

    const int tid  = threadIdx.x;
    const int lane = tid & 63;
    const int wave = tid >> 6;
    const int wm = wave >> 2;   // 0..1 -> rows wm*128 of the 256-row tile
    const int wn = wave & 3;    // 0..3 -> cols wn*64

    // T1: bijective XCD swizzle (nwg=1024, 1024%8==0), m-fast within XCD:
    // each XCD owns nt pair {2x,2x+1} x all 64 mt -> B footprint 4MB ~ L2.
    const int wg = (blockIdx.x & 7) * 128 + (blockIdx.x >> 3);
    const int mt = wg & 63;
    const int nt = wg >> 6;
    const int m0 = mt * BM;
    const int n0 = nt * BN;

    // ---- staging addressing (per thread) ----
    const int srow = tid >> 3;                                  // 0..63
    const int scb  = ((tid & 7) * 16) ^ (((tid >> 3) & 7) << 4); // pre-swizzled src col
    const char* gA = (const char*)A  + ((size_t)(m0 + srow) * K_TOT) * 2 + scb;
    const char* gB = (const char*)Bw + ((size_t)(n0 + srow) * K_TOT) * 2 + scb;
    char* lA = (char*)lds + tid * 16;            // + p*65536 + region*8192
    char* lB = (char*)lds + 32768 + tid * 16;

    auto stA = [&](int t, int h) {               // stage A half-tile h of tile t
        if (t >= NT) t -= 2;                     // parity-preserving clamp
        const int p = t & 1;
        const size_t kb = (size_t)t * (BK * 2);
#pragma unroll
        for (int s = 0; s < 2; ++s) {
            const int r = 2 * h + s;             // 64-row region 0..3
            __builtin_amdgcn_global_load_lds(
                (const __attribute__((address_space(1))) void*)
                    (gA + kb + (size_t)r * 64 * K_TOT * 2),
                (__attribute__((address_space(3))) void*)
                    (lA + p * 65536 + r * 8192), 16, 0, 0);
        }
    };
    auto stB = [&](int t, int h) {
        if (t >= NT) t -= 2;
        const int p = t & 1;
        const size_t kb = (size_t)t * (BK * 2);
#pragma unroll
        for (int s = 0; s < 2; ++s) {
            const int r = 2 * h + s;
            __builtin_amdgcn_global_load_lds(
                (const __attribute__((address_space(1))) void*)
                    (gB + kb + (size_t)r * 64 * K_TOT * 2),
                (__attribute__((address_space(3))) void*)
                    (lB + p * 65536 + r * 8192), 16, 0, 0);
        }
    };

    // ---- fragment read addressing ----
    // Fragment (16x16x32): lane l holds row (l&15), k = (l>>4)*8 + j.
    // phys byte col = (kk*64 + (l>>4)*16) ^ ((row&7)<<4); row&7 == lane&7.
    const int swz  = (lane & 7) << 4;
    const int pcb0 = (((lane >> 4) * 16) + 0)  ^ swz;   // k-slice 0
    const int pcb1 = (((lane >> 4) * 16) + 64) ^ swz;   // k-slice 1
    int arow[8], brow[4];
#pragma unroll
    for (int i = 0; i < 8; ++i) arow[i] = (wm * 128 + i * 16 + (lane & 15)) * 128;
#pragma unroll
    for (int j = 0; j < 4; ++j) brow[j] = (wn * 64 + j * 16 + (lane & 15)) * 128;

    f32x4 acc[8][4] = {};

    const char* ldsA0 = (const char*)lds;
    const char* ldsB0 = (const char*)lds + 32768;
    const char* ldsA1 = (const char*)lds + 65536;
    const char* ldsB1 = (const char*)lds + 98304;

// One tile = 4 phases. STG1..4 are this tile's stage slots.
#define TILE_BLOCK(Ap, Bp, STG1, STG2, STG3, STG4) do { \
    bf16x8 bF[4][2]; bf16x8 a67[2][2]; \
    { /* phase q0: read all B + A-q0, compute m 0,1 */ \
        bf16x8 a01[2][2]; \
        _Pragma("unroll") \
        for (int j_ = 0; j_ < 4; ++j_) { \
            bF[j_][0] = *(const bf16x8*)((Bp) + brow[j_] + pcb0); \
            bF[j_][1] = *(const bf16x8*)((Bp) + brow[j_] + pcb1); \
        } \
        _Pragma("unroll") \
        for (int m_ = 0; m_ < 2; ++m_) { \
            a01[m_][0] = *(const bf16x8*)((Ap) + arow[m_] + pcb0); \
            a01[m_][1] = *(const bf16x8*)((Ap) + arow[m_] + pcb1); \
        } \
        STG1; \
        BARF(); \
        __builtin_amdgcn_s_setprio(1); \
        MFMA_PAIR(0, a01[0], a01[1]); \
        __builtin_amdgcn_s_setprio(0); \
        BARF(); \
    } \
    { /* phase q1: read A-q1, compute m 2,3 */ \
        bf16x8 a23[2][2]; \
        _Pragma("unroll") \
        for (int m_ = 0; m_ < 2; ++m_) { \
            a23[m_][0] = *(const bf16x8*)((Ap) + arow[2 + m_] + pcb0); \
            a23[m_][1] = *(const bf16x8*)((Ap) + arow[2 + m_] + pcb1); \
        } \
        STG2; \
        BARF(); \
        __builtin_amdgcn_s_setprio(1); \
        MFMA_PAIR(2, a23[0], a23[1]); \
        __builtin_amdgcn_s_setprio(0); \
        BARF(); \
    } \
    { /* phase q2: read A-q2 AND A-q3 (A region dead after this phase) */ \
        bf16x8 a45[2][2]; \
        _Pragma("unroll") \
        for (int m_ = 0; m_ < 2; ++m_) { \
            a45[m_][0] = *(const bf16x8*)((Ap) + arow[4 + m_] + pcb0); \
            a45[m_][1] = *(const bf16x8*)((Ap) + arow[4 + m_] + pcb1); \
            a67[m_][0] = *(const bf16x8*)((Ap) + arow[6 + m_] + pcb0); \
            a67[m_][1] = *(const bf16x8*)((Ap) + arow[6 + m_] + pcb1); \
        } \
        STG3; \
        BARF(); \
        __builtin_amdgcn_s_setprio(1); \
        MFMA_PAIR(4, a45[0], a45[1]); \
        __builtin_amdgcn_s_setprio(0); \
        BARF(); \
    } \
    { /* phase q3: no reads; counted vmcnt before the trailing barrier */ \
        STG4; \
        BARF(); \
        __builtin_amdgcn_s_setprio(1); \
        MFMA_PAIR(6, a67[0], a67[1]); \
        __builtin_amdgcn_s_setprio(0); \
        VMW(6); \
        BARF(); \
    } \
} while (0)

    // Prologue: tile0 fully (8 loads) + tile1 {BH0,BH1,AH0} (6 loads);
    // vmcnt(6) -> tile0 complete, 3 half-tiles of tile1 in flight.
    stB(0, 0); stB(0, 1); stA(0, 0); stA(0, 1);
    stB(1, 0); stB(1, 1); stA(1, 0);
    VMW(6);
    BARF();

    for (int it = 0; it < NT / 2; ++it) {
        const int ta = 2 * it, tb = ta + 1;
        TILE_BLOCK(ldsA0, ldsB0,
                   stA(tb, 1), stB(ta + 2, 0), stB(ta + 2, 1), stA(ta + 2, 0));
        TILE_BLOCK(ldsA1, ldsB1,
                   stA(ta + 2, 1), stB(tb + 2, 0), stB(tb + 2, 1), stA(tb + 2, 0));
    }
#undef TILE_BLOCK

    // Drain stray clamped prefetches before reusing nothing (cheap, once).
    VMW(0);
    BARF();

    // Epilogue: C/D layout col=lane&15, row=(lane>>4)*4+reg (m89-verified).
    const int cl = lane & 15;
    const int rq = (lane >> 4) * 4;
#pragma unroll
    for (int j = 0; j < 4; ++j) {
        const int col = n0 + wn * 64 + j * 16 + cl;
        const float bv = bias[col];
#pragma unroll
        for (int i = 0; i < 8; ++i) {
            const size_t rbase = (size_t)(m0 + wm * 128 + i * 16 + rq);
#pragma unroll
            for (int r = 0; r < 4; ++r) {
                C[(rbase + r) * N_TOT + col] = acc[i][j][r] + bv;
            }
        }
    }
}

// ---------------------------------------------------------------------------
extern "C" void kernel_launch(void* const* d_in, const int* in_sizes, int n_in,
                              void* d_out, int out_size, void* d_ws, size_t ws_size,
                              hipStream_t stream) {
    const float* x      = (const float*)d_in[0];
    const int*   wp     = (const int*)d_in[1];
    const float* wscale = (const float*)d_in[2];   // fp16 promoted to f32 by harness
    const int*   wmask  = (const int*)d_in[3];     // bool promoted to int32
    const float* bias   = (const float*)d_in[4];
    float*       out    = (float*)d_out;

    // Workspace: W bf16 (32 MB) at offset 0, x bf16 (128 MB) after.
    __hip_bfloat16* Wb = (__hip_bfloat16*)d_ws;
    __hip_bfloat16* Xb = (__hip_bfloat16*)((char*)d_ws + (size_t)N_TOT * K_TOT * 2);

    // 1) dequant W: NB*4 threads
    dequant_w<<<(NB * 4) / 256, 256, 0, stream>>>(wp, wscale, wmask, Wb);
    // 2) convert x: M*K/8 threads
    cvt_x<<<((size_t)M_TOT * K_TOT / 8) / 256, 256, 0, stream>>>(x, Xb);
    // 3) GEMM: 64 x 16 tiles of 256x256, 512 threads (8 waves)
    gemm_bt<<<(M_TOT / BM) * (N_TOT / BN), 512, 0, stream>>>(Xb, Wb, bias, out);
}

// Round 2
// 896.979 us; speedup vs baseline: 1.0071x; 1.0071x over previous
//
#include <hip/hip_runtime.h>
#include <hip/hip_bf16.h>
#include <stdint.h>

// Problem constants (from reference): B=8,S=2048,IN=4096,OUT=4096,G=32
#define M_TOT 16384   // B*S
#define N_TOT 4096    // OUT
#define K_TOT 4096    // IN
#define NB    524288  // OUT*IN/G

// GEMM geometry: 256x256 tile, BK=64, 8 waves (2M x 4N), 8-phase schedule
// with A-fragment reads pipelined one phase ahead + 1 barrier/phase.
#define BM 256
#define BN 256
#define BK 64
#define NT (K_TOT / BK)   // 64 K-tiles

typedef __attribute__((ext_vector_type(8))) __bf16 bf16x8;
typedef __attribute__((ext_vector_type(4))) float f32x4;

// Raw s_barrier with compiler memory fences on both sides (ds_read/ds_write
// and global_load_lds must not be moved across by the scheduler).
#define BARF() do { asm volatile("" ::: "memory"); \
                    __builtin_amdgcn_s_barrier(); \
                    asm volatile("" ::: "memory"); } while (0)
#define VMW(n) asm volatile("s_waitcnt vmcnt(" #n ")" ::: "memory")

#define MFMA1(d, a, b) d = __builtin_amdgcn_mfma_f32_16x16x32_bf16(a, b, d, 0, 0, 0)
// One C-quadrant (2 m-frags x 4 n-frags) x K=64 (2 k-slices) = 16 MFMA.
#define MFMA_PAIR(mb, A0, A1) do { \
  _Pragma("unroll") \
  for (int j_ = 0; j_ < 4; ++j_) { \
    MFMA1(acc[mb][j_],     A0[0], bF[j_][0]); \
    MFMA1(acc[mb][j_],     A0[1], bF[j_][1]); \
    MFMA1(acc[(mb)+1][j_], A1[0], bF[j_][0]); \
    MFMA1(acc[(mb)+1][j_], A1[1], bF[j_][1]); \
  } \
} while (0)

// ---------------------------------------------------------------------------
// Kernel 1: dequantize int4-packed W -> bf16 [OUT, IN] row-major. (unchanged)
// ---------------------------------------------------------------------------
__global__ __launch_bounds__(256) void dequant_w(
    const int* __restrict__ packed,          // [NB, 16] int32, one byte each
    const float* __restrict__ scale,         // [NB] f32 (promoted from fp16)
    const int* __restrict__ mask,            // [NB] int32 (promoted from bool)
    __hip_bfloat16* __restrict__ wout)       // [OUT*IN] bf16
{
    int t = blockIdx.x * blockDim.x + threadIdx.x;   // 0 .. NB*4-1
    const int4 pk = ((const int4*)packed)[t];
    int nb = t >> 2;
    float se = scale[nb] * (mask[nb] ? 1.0f : 0.5f);
    int vals[4] = { pk.x, pk.y, pk.z, pk.w };
    __hip_bfloat16 o[8];
#pragma unroll
    for (int j = 0; j < 4; ++j) {
        int v = vals[j];
        o[2*j]   = __float2bfloat16((float)((v & 0xF) - 8) * se);
        o[2*j+1] = __float2bfloat16((float)(((v >> 4) & 0xF) - 8) * se);
    }
    int4 st;
    __builtin_memcpy(&st, o, 16);
    ((int4*)wout)[t] = st;
}

// ---------------------------------------------------------------------------
// Kernel 2: x fp32 -> bf16. (unchanged)
// ---------------------------------------------------------------------------
__global__ __launch_bounds__(256) void cvt_x(
    const float* __restrict__ x, __hip_bfloat16* __restrict__ xb)
{
    int t = blockIdx.x * blockDim.x + threadIdx.x;   // each handles 8 elems
    const float4* xp = (const float4*)x;
    float4 a = xp[2*t], b = xp[2*t + 1];
    __hip_bfloat16 o[8] = {
        __float2bfloat16(a.x), __float2bfloat16(a.y),
        __float2bfloat16(a.z), __float2bfloat16(a.w),
        __float2bfloat16(b.x), __float2bfloat16(b.y),
        __float2bfloat16(b.z), __float2bfloat16(b.w)
    };
    int4 st;
    __builtin_memcpy(&st, o, 16);
    ((int4*)xb)[t] = st;
}

// ---------------------------------------------------------------------------
// Kernel 3: C[M,N] = A[M,K] * W[N,K]^T + bias.  256x256, 8 waves, BK=64.
//
// Round-2 schedule (vs round 1): A-frag ds_reads pipelined one phase ahead;
// ONE barrier per phase (8/iter, was 16); stage slots re-derived so every
// cross-phase-consumed ds_read targets a region that is never staged while
// in flight.  Register-budget-neutral: peak live frags = 64 regs (same as
// round 1's q2), VGPR stays ~128 + 128 AGPR = the 2-waves/SIMD cap.
//
// Iteration i computes T0=2i (buf0, phases p1-p4) and T1=2i+1 (buf1, p5-p8).
//   reads:  p1: B(T0) 8 + a01 4 + a23 4   (B+a01 consumed p1; a23 -> p2)
//           p2: a45 (-> p3)    p3: a67 (-> p4)    p4: none
//           p5-p8: same for T1
//   stages: p1: A(T1) 4        p2: B(T2)H0 2      p3: B(T2)H1 2
//           p5: A(T2) 4        p6: B(T3)H0 2      p7: B(T3)H1 2
//   vmcnt(4) at p4 end: outstanding {A(T0)p5',B(T1)p6',p7', A(T1)p1,
//     B(T2)p2,p3}=16 -> completes through A(T1) (buf1 fully resident for
//     p5's reads), leaves p2,p3 in flight.  Symmetric vmcnt(4) at p8 end
//     (completes B(T2)+A(T2) for next p1).  Leads: A 3-4 phases, B 6-7.
//   Stage-deadness: every staged region's last ds_read is consumed by an
//     MFMA *before* the barrier preceding the stage (checked per slot);
//     in-flight cross-phase reads (a23/a45/a67) target the A region, which
//     is only staged at p5/p1 after its a67 was consumed at p4/p8.
//   Tail: staged tile >= NT clamps t-=2 = the tile already resident in that
//     buffer -> identical bytes, harmless regardless of timing.
// ---------------------------------------------------------------------------
__global__ __launch_bounds__(512, 2) void gemm_bt(
    const __hip_bfloat16* __restrict__ A,   // [M_TOT, K_TOT] bf16
    const __hip_bfloat16* __restrict__ Bw,  // [N_TOT, K_TOT] bf16
    const float* __restrict__ bias,         // [N_TOT]
    float* __restrict__ C)                  // [M_TOT, N_TOT]
{
    __shared__ __align__(16) char lds[131072];

    const int tid  = threadIdx.x;
    const int lane = tid & 63;
    const int wave = tid >> 6;
    const int wm = wave >> 2;   // 0..1 -> rows wm*128 of the 256-row tile
    const int wn = wave & 3;    // 0..3 -> cols wn*64

    // T1: bijective XCD swizzle (nwg=1024, 1024%8==0), m-fast within XCD:
    // each XCD owns nt pair {2x,2x+1} x all 64 mt -> B footprint 4MB ~ L2.
    const int wg = (blockIdx.x & 7) * 128 + (blockIdx.x >> 3);
    const int mt = wg & 63;
    const int nt = wg >> 6;
    const int m0 = mt * BM;
    const int n0 = nt * BN;

    // ---- staging addressing (per thread) ----
    // T2 swizzle: logical (row, byte-col cb) stored at cb ^ ((row&7)<<4).
    // global_load_lds dest is LINEAR; source col pre-swizzled (rule 21).
    const int srow = tid >> 3;                                   // 0..63
    const int scb  = ((tid & 7) * 16) ^ (((tid >> 3) & 7) << 4); // pre-swz src col
    const char* gA = (const char*)A  + ((size_t)(m0 + srow) * K_TOT) * 2 + scb;
    const char* gB = (const char*)Bw + ((size_t)(n0 + srow) * K_TOT) * 2 + scb;
    char* lA = (char*)lds + tid * 16;            // + p*65536 + region*8192
    char* lB = (char*)lds + 32768 + tid * 16;

    auto stA4 = [&](int t) {                     // stage full A tile (4 loads)
        if (t >= NT) t -= 2;                     // parity-preserving clamp
        const int p = t & 1;
        const size_t kb = (size_t)t * (BK * 2);
#pragma unroll
        for (int r = 0; r < 4; ++r) {
            __builtin_amdgcn_global_load_lds(
                (const __attribute__((address_space(1))) void*)
                    (gA + kb + (size_t)r * 64 * K_TOT * 2),
                (__attribute__((address_space(3))) void*)
                    (lA + p * 65536 + r * 8192), 16, 0, 0);
        }
    };
    auto stB2 = [&](int t, int h) {              // stage B half-tile (2 loads)
        if (t >= NT) t -= 2;
        const int p = t & 1;
        const size_t kb = (size_t)t * (BK * 2);
#pragma unroll
        for (int s = 0; s < 2; ++s) {
            const int r = 2 * h + s;
            __builtin_amdgcn_global_load_lds(
                (const __attribute__((address_space(1))) void*)
                    (gB + kb + (size_t)r * 64 * K_TOT * 2),
                (__attribute__((address_space(3))) void*)
                    (lB + p * 65536 + r * 8192), 16, 0, 0);
        }
    };

    // ---- fragment read addressing ----
    // Fragment (16x16x32): lane l holds row (l&15), k = (l>>4)*8 + j.
    // phys byte col = (kk*64 + (l>>4)*16) ^ ((row&7)<<4); row&7 == lane&7.
    const int swz  = (lane & 7) << 4;
    const int pcb0 = (((lane >> 4) * 16) + 0)  ^ swz;   // k-slice 0
    const int pcb1 = (((lane >> 4) * 16) + 64) ^ swz;   // k-slice 1
    int arow[8], brow[4];
#pragma unroll
    for (int i = 0; i < 8; ++i) arow[i] = (wm * 128 + i * 16 + (lane & 15)) * 128;
#pragma unroll
    for (int j = 0; j < 4; ++j) brow[j] = (wn * 64 + j * 16 + (lane & 15)) * 128;

    f32x4 acc[8][4] = {};

    const char* ldsA0 = (const char*)lds;
    const char* ldsB0 = (const char*)lds + 32768;
    const char* ldsA1 = (const char*)lds + 65536;
    const char* ldsB1 = (const char*)lds + 98304;

// One tile = 4 phases, 1 barrier each.  aCur/aNxt rotate (static idx, rule 20).
#define TILE_BLOCK(Ap, Bp, STG_A, STG_B0, STG_B1) do { \
    bf16x8 bF[4][2], aCur[2][2], aNxt[2][2]; \
    /* p1: reads B(8)+a01(4)+a23(4); stage A; MFMA m01 (B+a01 same-phase) */ \
    _Pragma("unroll") \
    for (int j_ = 0; j_ < 4; ++j_) { \
        bF[j_][0] = *(const bf16x8*)((Bp) + brow[j_] + pcb0); \
        bF[j_][1] = *(const bf16x8*)((Bp) + brow[j_] + pcb1); \
    } \
    _Pragma("unroll") \
    for (int m_ = 0; m_ < 2; ++m_) { \
        aCur[m_][0] = *(const bf16x8*)((Ap) + arow[m_] + pcb0); \
        aCur[m_][1] = *(const bf16x8*)((Ap) + arow[m_] + pcb1); \
        aNxt[m_][0] = *(const bf16x8*)((Ap) + arow[2 + m_] + pcb0); \
        aNxt[m_][1] = *(const bf16x8*)((Ap) + arow[2 + m_] + pcb1); \
    } \
    STG_A; \
    __builtin_amdgcn_s_setprio(1); MFMA_PAIR(0, aCur[0], aCur[1]); \
    __builtin_amdgcn_s_setprio(0); \
    BARF(); \
    /* p2: read a45 (ahead); stage B'H0; MFMA m23 on aNxt (read last phase) */ \
    _Pragma("unroll") \
    for (int m_ = 0; m_ < 2; ++m_) { \
        aCur[m_][0] = *(const bf16x8*)((Ap) + arow[4 + m_] + pcb0); \
        aCur[m_][1] = *(const bf16x8*)((Ap) + arow[4 + m_] + pcb1); \
    } \
    STG_B0; \
    __builtin_amdgcn_s_setprio(1); MFMA_PAIR(2, aNxt[0], aNxt[1]); \
    __builtin_amdgcn_s_setprio(0); \
    BARF(); \
    /* p3: read a67 (ahead); stage B'H1; MFMA m45 on aCur */ \
    _Pragma("unroll") \
    for (int m_ = 0; m_ < 2; ++m_) { \
        aNxt[m_][0] = *(const bf16x8*)((Ap) + arow[6 + m_] + pcb0); \
        aNxt[m_][1] = *(const bf16x8*)((Ap) + arow[6 + m_] + pcb1); \
    } \
    STG_B1; \
    __builtin_amdgcn_s_setprio(1); MFMA_PAIR(4, aCur[0], aCur[1]); \
    __builtin_amdgcn_s_setprio(0); \
    BARF(); \
    /* p4: no reads/stages; MFMA m67 on aNxt; counted vmcnt */ \
    __builtin_amdgcn_s_setprio(1); MFMA_PAIR(6, aNxt[0], aNxt[1]); \
    __builtin_amdgcn_s_setprio(0); \
    VMW(4); \
    BARF(); \
} while (0)

    // Prologue: B(T0) + A(T0) + B(T1) = 12 loads; vmcnt(4) completes T0's
    // 8 (B+A resident), leaves B(T1)'s 4 in flight -> steady-state pattern.
    stB2(0, 0); stB2(0, 1); stA4(0); stB2(1, 0); stB2(1, 1);
    VMW(4);
    BARF();

    for (int it = 0; it < NT / 2; ++it) {
        const int ta = 2 * it, tb = ta + 1;
        TILE_BLOCK(ldsA0, ldsB0, stA4(tb),     stB2(ta + 2, 0), stB2(ta + 2, 1));
        TILE_BLOCK(ldsA1, ldsB1, stA4(ta + 2), stB2(tb + 2, 0), stB2(tb + 2, 1));
    }
#undef TILE_BLOCK

    // Epilogue: C/D layout col=lane&15, row=(lane>>4)*4+reg (m89-verified).
    // No pre-drain: stray tail prefetches only touch LDS, which is dead now.
    const int cl = lane & 15;
    const int rq = (lane >> 4) * 4;
#pragma unroll
    for (int j = 0; j < 4; ++j) {
        const int col = n0 + wn * 64 + j * 16 + cl;
        const float bv = bias[col];
#pragma unroll
        for (int i = 0; i < 8; ++i) {
            const size_t rbase = (size_t)(m0 + wm * 128 + i * 16 + rq);
#pragma unroll
            for (int r = 0; r < 4; ++r) {
                C[(rbase + r) * N_TOT + col] = acc[i][j][r] + bv;
            }
        }
    }
    // Safety: drain LDS-DMA before endpgm so a successor block on this CU
    // can't see a stray late write into its freshly-allocated LDS.
    VMW(0);
}

// ---------------------------------------------------------------------------
extern "C" void kernel_launch(void* const* d_in, const int* in_sizes, int n_in,
                              void* d_out, int out_size, void* d_ws, size_t ws_size,
                              hipStream_t stream) {
    const float* x      = (const float*)d_in[0];
    const int*   wp     = (const int*)d_in[1];
    const float* wscale = (const float*)d_in[2];   // fp16 promoted to f32 by harness
    const int*   wmask  = (const int*)d_in[3];     // bool promoted to int32
    const float* bias   = (const float*)d_in[4];
    float*       out    = (float*)d_out;

    // Workspace: W bf16 (32 MB) at offset 0, x bf16 (128 MB) after.
    __hip_bfloat16* Wb = (__hip_bfloat16*)d_ws;
    __hip_bfloat16* Xb = (__hip_bfloat16*)((char*)d_ws + (size_t)N_TOT * K_TOT * 2);

    // 1) dequant W: NB*4 threads
    dequant_w<<<(NB * 4) / 256, 256, 0, stream>>>(wp, wscale, wmask, Wb);
    // 2) convert x: M*K/8 threads
    cvt_x<<<((size_t)M_TOT * K_TOT / 8) / 256, 256, 0, stream>>>(x, Xb);
    // 3) GEMM: 64 x 16 tiles of 256x256, 512 threads (8 waves)
    gemm_bt<<<(M_TOT / BM) * (N_TOT / BN), 512, 0, stream>>>(Xb, Wb, bias, out);
}